// Round 19
// baseline (117.058 us; speedup 1.0000x reference)
//
#include <hip/hip_runtime.h>

#define LRELU_ALPHA 0.2f
#define NN 4096
#define CAP 256

typedef unsigned short u16;
typedef short bf16x8 __attribute__((ext_vector_type(8)));
typedef float f32x4 __attribute__((ext_vector_type(4)));
typedef u16 u16x4 __attribute__((ext_vector_type(4)));
typedef u16 u16x2 __attribute__((ext_vector_type(2)));
typedef u16 u16x8 __attribute__((ext_vector_type(8)));

__device__ __forceinline__ u16 f2bf(float f) {
  unsigned u = __float_as_uint(f);
  u += 0x7FFFu + ((u >> 16) & 1u);
  return (u16)(u >> 16);
}
__device__ __forceinline__ float bf2f(u16 u) {
  return __uint_as_float(((unsigned)u) << 16);
}

// butterfly reductions: result valid in ALL 64 lanes
__device__ __forceinline__ float waveSum(float v) {
  #pragma unroll
  for (int o = 32; o > 0; o >>= 1) v += __shfl_xor(v, o, 64);
  return v;
}
__device__ __forceinline__ float waveMax(float v) {
  #pragma unroll
  for (int o = 32; o > 0; o >>= 1) v = fmaxf(v, __shfl_xor(v, o, 64));
  return v;
}

__device__ __forceinline__ void gload_lds16(const void* g, void* l) {
  __builtin_amdgcn_global_load_lds((const __attribute__((address_space(1))) void*)g,
                                   (__attribute__((address_space(3))) void*)l, 16, 0, 0);
}

// LDS-only barrier (no vmcnt drain): epilogue global stores keep flying
__device__ __forceinline__ void lds_barrier() {
  asm volatile("s_waitcnt lgkmcnt(0)" ::: "memory");
  __builtin_amdgcn_s_barrier();
}

// ---- dedicated CSR build: one block per row, tiny LDS -> full occupancy,
//      wave-local inclusive scan + 4-entry cross-wave combine (4 barriers total)
__global__ __launch_bounds__(256) void build_csr(const unsigned* __restrict__ adjw,
                                                 int* __restrict__ nbr,
                                                 int* __restrict__ cnt)
{
  __shared__ int wsum[4];
  const int i = blockIdx.x, tid = threadIdx.x;
  const int w = tid >> 6, lane = tid & 63;
  unsigned bits = 0;
  const unsigned* row = adjw + (size_t)i * 4096 + tid * 16;
  #pragma unroll
  for (int ck = 0; ck < 4; ++ck) {
    uint4 v = *(const uint4*)(row + ck * 4);
    if (v.x) bits |= 1u << (ck * 4 + 0);
    if (v.y) bits |= 1u << (ck * 4 + 1);
    if (v.z) bits |= 1u << (ck * 4 + 2);
    if (v.w) bits |= 1u << (ck * 4 + 3);
  }
  int mycnt = __popc(bits);
  // wave-local exclusive prefix via mbcnt-style: inclusive scan with shfl_up
  int incl = mycnt;
  #pragma unroll
  for (int o = 1; o < 64; o <<= 1) {
    int v = __shfl_up(incl, o, 64);
    if (lane >= o) incl += v;
  }
  if (lane == 63) wsum[w] = incl;
  __syncthreads();
  int base = 0;
  #pragma unroll
  for (int k = 0; k < 4; ++k) base += (k < w) ? wsum[k] : 0;
  const int total = wsum[0] + wsum[1] + wsum[2] + wsum[3];
  int pos = base + incl - mycnt;
  #pragma unroll
  for (int b = 0; b < 16; ++b) {
    if (bits & (1u << b)) {
      if (pos < CAP) nbr[(size_t)i * CAP + pos] = tid * 16 + b;
      ++pos;
    }
  }
  if (tid == 0) cnt[i] = total;
}

// ---- transpose helper (flat 256 threads): Wt[n][k] (bf16, ld=Kpad) from W[k][n] (f32)
__device__ __forceinline__ void transpose_body(const float* Wsrc, u16* Wt,
                                               int K, int N, int Kpad,
                                               int bx, int by, float (*t)[33]) {
  const int kb = by * 32, nb = bx * 32;
  const int tx = threadIdx.x & 31, ty = threadIdx.x >> 5;  // 32 x 8
  for (int i = ty; i < 32; i += 8) {
    int k = kb + i, n = nb + tx;
    t[i][tx] = (k < K && n < N) ? Wsrc[(size_t)k * N + n] : 0.f;
  }
  __syncthreads();
  for (int i = ty; i < 32; i += 8) {
    int n = nb + i, k = kb + tx;
    if (n < N && k < Kpad) Wt[(size_t)n * Kpad + k] = f2bf(t[tx][i]);
  }
}

// ---- weight transposes (incl fc2) + X f32->bf16 + fs/fd zero
// [0,512) W0 | [512,656) W1 | [656,800) W2 | [800,960) fc1 | [960,3008) fc2 |
// [3008,7104) X | [7104,7128) zero
__global__ __launch_bounds__(256) void prep_all(
    const float* __restrict__ W0, u16* __restrict__ W0t,
    const float* __restrict__ W1, u16* __restrict__ W1t,
    const float* __restrict__ W2, u16* __restrict__ W2t,
    const float* __restrict__ fc1w, u16* __restrict__ fc1t,
    const float* __restrict__ fc2w, u16* __restrict__ fc2t,
    const float* __restrict__ X, u16* __restrict__ Xb,
    float* __restrict__ fsz)
{
  __shared__ float t[32][33];
  const int i = blockIdx.x, tid = threadIdx.x;
  if (i < 512) {
    transpose_body(W0, W0t, 1024, 512, 1024, i & 15, i >> 4, t);
  } else if (i < 656) {
    int j = i - 512;   // 8 x 18
    transpose_body(W1, W1t, 528, 256, 576, j & 7, j >> 3, t);
  } else if (i < 800) {
    int j = i - 656;
    transpose_body(W2, W2t, 528, 256, 576, j & 7, j >> 3, t);
  } else if (i < 960) {
    int j = i - 800;   // 16 x 10
    transpose_body(fc1w, fc1t, 272, 512, 320, j & 15, j >> 4, t);
  } else if (i < 3008) {
    int j = i - 960;   // fc2: 128 x 16
    transpose_body(fc2w, fc2t, 512, 4096, 512, j & 127, j >> 7, t);
  } else if (i < 7104) {
    int j = i - 3008;
    int idx = j * 256 + tid;
    float4 v = ((const float4*)X)[idx];
    u16x4 o = {f2bf(v.x), f2bf(v.y), f2bf(v.z), f2bf(v.w)};
    ((u16x4*)Xb)[idx] = o;
  } else {
    int j = i - 7104;   // zero fs0..fd2: 6*4096 f32 = 6144 float4
    ((f32x4*)fsz)[j * 256 + tid] = f32x4{0.f, 0.f, 0.f, 0.f};
  }
}

// ---- bf16 MFMA GEMM 128x64 tile, BK=64, dbuf + counted vmcnt, pipelined epilogue,
//      XCD swizzle, optional fused attention-score reduction (atomicAdd into fs/fd).
// FS: 0 = none; 1 = single (aA[0:512]=src,[512:1024]=dst -> fsA/fdA);
//     2 = dual halves (cols<256: aA/fsA/fdA, cols>=256: aB/fsB/fdB; a layout [0:256|256:512])
template<int ACT, bool OBF, int FS>
__device__ __forceinline__ void gemm64_dev(
    const u16* __restrict__ A, int lda,
    const u16* __restrict__ Bt, int ldb,
    void* __restrict__ Cout, int ldc,
    int K, const float* __restrict__ bias,
    u16 (&As)[2][128 * 64], u16 (&Bs)[2][64 * 64], int bid,
    const float* aA, const float* aB,
    float* fsA, float* fdA, float* fsB, float* fdB)
{
  const int tid = threadIdx.x;
  const int lane = tid & 63, wv = tid >> 6;
  const int wm = wv >> 1, wn = wv & 1;
  const int swz = ((bid & 7) << 5) | (bid >> 3);
  const int m0 = (swz >> 3) * 128, n0 = (swz & 7) * 64;
  const int nk = K >> 6;

  f32x4 acc[4][2] = {};

  auto STAGE = [&](int buf, int kt) {   // 6 loads/thread
    #pragma unroll
    for (int i = 0; i < 4; ++i) {       // A: 128 rows x 8 slots
      int c = tid + i * 256;
      int r = c >> 3, sl = c & 7;
      int sg = sl ^ (r & 7);
      gload_lds16(A + (size_t)(m0 + r) * lda + kt * 64 + sg * 8, (char*)As[buf] + (c & ~63) * 16);
    }
    #pragma unroll
    for (int i = 0; i < 2; ++i) {       // B: 64 rows x 8 slots
      int c = tid + i * 256;
      int r = c >> 3, sl = c & 7;
      int sg = sl ^ (r & 7);
      gload_lds16(Bt + (size_t)(n0 + r) * ldb + kt * 64 + sg * 8, (char*)Bs[buf] + (c & ~63) * 16);
    }
  };

  STAGE(0, 0);
  if (nk > 1) STAGE(1, 1);

  int cur = 0;
  for (int kt = 0; kt < nk; ++kt) {
    if (kt + 1 < nk) { asm volatile("s_waitcnt vmcnt(6)" ::: "memory"); }
    else             { asm volatile("s_waitcnt vmcnt(0)" ::: "memory"); }
    __builtin_amdgcn_s_barrier();

    #pragma unroll
    for (int ks = 0; ks < 2; ++ks) {
      bf16x8 af[4], bf_[2];
      #pragma unroll
      for (int mi = 0; mi < 4; ++mi) {
        int r = wm * 64 + mi * 16 + (lane & 15);
        int sl = (ks * 4 + (lane >> 4)) ^ (r & 7);
        af[mi] = *(const bf16x8*)((const char*)As[cur] + r * 128 + sl * 16);
      }
      #pragma unroll
      for (int ni = 0; ni < 2; ++ni) {
        int r = wn * 32 + ni * 16 + (lane & 15);
        int sl = (ks * 4 + (lane >> 4)) ^ (r & 7);
        bf_[ni] = *(const bf16x8*)((const char*)Bs[cur] + r * 128 + sl * 16);
      }
      __builtin_amdgcn_s_setprio(1);
      #pragma unroll
      for (int mi = 0; mi < 4; ++mi)
        #pragma unroll
        for (int ni = 0; ni < 2; ++ni)
          acc[mi][ni] = __builtin_amdgcn_mfma_f32_16x16x32_bf16(af[mi], bf_[ni], acc[mi][ni], 0, 0, 0);
      __builtin_amdgcn_s_setprio(0);
    }

    __builtin_amdgcn_s_barrier();
    if (kt + 2 < nk) STAGE(cur, kt + 2);
    cur ^= 1;
  }

  float bv2[2];
  #pragma unroll
  for (int ni = 0; ni < 2; ++ni)
    bv2[ni] = bias ? bias[n0 + wn * 32 + ni * 16 + (lane & 15)] : 0.f;
  float* sc = (float*)As;
  #pragma unroll
  for (int mi = 0; mi < 4; ++mi) {
    lds_barrier();
    const int lr = wm * 16 + (lane >> 4) * 4;
    #pragma unroll
    for (int ni = 0; ni < 2; ++ni) {
      const int lc = wn * 32 + ni * 16 + (lane & 15);
      #pragma unroll
      for (int j = 0; j < 4; ++j) {
        float v = acc[mi][ni][j] + bv2[ni];
        if (ACT == 1) v = fmaxf(v, 0.f);
        if (ACT == 2) v = 1.f / (1.f + __expf(-v));
        sc[(lr + j) * 64 + lc] = v;
      }
    }
    lds_barrier();
    // fused attention-score partials from the staged f32 band
    if constexpr (FS > 0) {
      const float* aS; const float* aD; float* fsO; float* fdO; int colbase;
      if constexpr (FS == 1) {
        aS = aA; aD = aA + 512; fsO = fsA; fdO = fdA; colbase = n0;
      } else {
        const bool lo2 = (n0 < 256);
        const float* av = lo2 ? aA : aB;
        aS = av; aD = av + 256;
        fsO = lo2 ? fsA : fsB; fdO = lo2 ? fdA : fdB;
        colbase = n0 & 255;
      }
      const int rr = tid >> 3, cg = tid & 7;
      float s0 = 0.f, s1 = 0.f;
      #pragma unroll
      for (int q = 0; q < 8; ++q) {
        float hv = sc[rr * 64 + cg * 8 + q];
        s0 = fmaf(hv, aS[colbase + cg * 8 + q], s0);
        s1 = fmaf(hv, aD[colbase + cg * 8 + q], s1);
      }
      #pragma unroll
      for (int o = 1; o < 8; o <<= 1) {
        s0 += __shfl_xor(s0, o, 64);
        s1 += __shfl_xor(s1, o, 64);
      }
      if (cg == 0) {
        int grow = m0 + (rr >> 4) * 64 + mi * 16 + (rr & 15);
        atomicAdd(fsO + grow, s0);
        atomicAdd(fdO + grow, s1);
      }
    }
    #pragma unroll
    for (int u = 0; u < 2; ++u) {
      int idx = tid + u * 256;
      int r = idx >> 4, c4 = (idx & 15) * 4;
      int grow = m0 + (r >> 4) * 64 + mi * 16 + (r & 15);
      float4 v4 = *(const float4*)(sc + r * 64 + c4);
      if (OBF) {
        u16x4 o = {f2bf(v4.x), f2bf(v4.y), f2bf(v4.z), f2bf(v4.w)};
        *(u16x4*)((u16*)Cout + (size_t)grow * ldc + n0 + c4) = o;
      } else {
        *(float4*)((float*)Cout + (size_t)grow * ldc + n0 + c4) = v4;
      }
    }
  }
}

template<int ACT, bool OBF, int FS>
__global__ __launch_bounds__(256) void gemm_mfma64(
    const u16* __restrict__ A, int lda, const u16* __restrict__ Bt, int ldb,
    void* __restrict__ Cout, int ldc, int K, const float* __restrict__ bias,
    const float* aA, const float* aB,
    float* fsA, float* fdA, float* fsB, float* fdB)
{
  __shared__ u16 As[2][128 * 64];
  __shared__ u16 Bs[2][64 * 64];
  gemm64_dev<ACT, OBF, FS>(A, lda, Bt, ldb, Cout, ldc, K, bias, As, Bs,
                           blockIdx.y * 8 + blockIdx.x, aA, aB, fsA, fdA, fsB, fdB);
}

// ---- fc2: 256x256 tile, BK=64, 8 waves, 8-PHASE counted-vmcnt schedule,
//      pipelined staged NT epilogue (64-row bands), XCD swizzle. K even*64.
__global__ __launch_bounds__(512, 2) void gemm_fc2_8p(
    const u16* __restrict__ A, int lda,
    const u16* __restrict__ Bt, int ldb,
    float* __restrict__ Cout, int ldc,
    int K, const float* __restrict__ bias)
{
  __shared__ u16 As[2][2][128 * 64];   // [slot][half] 16KB each -> 64KB
  __shared__ u16 Bs[2][2][128 * 64];   // 64KB
  const int tid = threadIdx.x;
  const int lane = tid & 63, wv = tid >> 6;
  const int wm = wv >> 2, wn = wv & 3;          // 2 x 4; wave owns 128x64
  const int bid = blockIdx.y * 16 + blockIdx.x;
  const int swz = ((bid & 7) << 5) | (bid >> 3);
  const int m0 = (swz >> 4) * 256, n0 = (swz & 15) * 256;
  const int nk = K >> 6;

  f32x4 acc[8][4] = {};

  auto stA = [&](int slot, int h, int t) {      // 2 loads/thread (one 128x64 half)
    const u16* Ap = A + (size_t)(m0 + h * 128) * lda + t * 64;
    #pragma unroll
    for (int i = 0; i < 2; ++i) {
      int c = tid + i * 512;
      int r = c >> 3, sl = c & 7;
      int sg = sl ^ (r & 7);
      gload_lds16(Ap + (size_t)r * lda + sg * 8, (char*)&As[slot][h][0] + (c & ~63) * 16);
    }
  };
  auto stB = [&](int slot, int h, int t) {
    const u16* Bp = Bt + (size_t)(n0 + h * 128) * ldb + t * 64;
    #pragma unroll
    for (int i = 0; i < 2; ++i) {
      int c = tid + i * 512;
      int r = c >> 3, sl = c & 7;
      int sg = sl ^ (r & 7);
      gload_lds16(Bp + (size_t)r * ldb + sg * 8, (char*)&Bs[slot][h][0] + (c & ~63) * 16);
    }
  };

  bf16x8 afl[4][2], afh[4][2], bfl[2][2], bfh[2][2];
  auto rdAq = [&](int slot, int mi0, bf16x8 (&dst)[4][2]) {
    #pragma unroll
    for (int m = 0; m < 4; ++m)
      #pragma unroll
      for (int ks = 0; ks < 2; ++ks) {
        int r = (mi0 + m) * 16 + (lane & 15);
        int sl = (ks * 4 + (lane >> 4)) ^ (r & 7);
        dst[m][ks] = *(const bf16x8*)((const char*)&As[slot][wm][0] + r * 128 + sl * 16);
      }
  };
  auto rdBq = [&](int slot, int ni0, bf16x8 (&dst)[2][2]) {
    #pragma unroll
    for (int n = 0; n < 2; ++n)
      #pragma unroll
      for (int ks = 0; ks < 2; ++ks) {
        int r = (wn & 1) * 64 + (ni0 + n) * 16 + (lane & 15);
        int sl = (ks * 4 + (lane >> 4)) ^ (r & 7);
        dst[n][ks] = *(const bf16x8*)((const char*)&Bs[slot][wn >> 1][0] + r * 128 + sl * 16);
      }
  };
  auto quad = [&](int mi0, int ni0, bf16x8 (&af)[4][2], bf16x8 (&bf)[2][2]) {
    __builtin_amdgcn_s_setprio(1);
    #pragma unroll
    for (int m = 0; m < 4; ++m)
      #pragma unroll
      for (int n = 0; n < 2; ++n)
        #pragma unroll
        for (int ks = 0; ks < 2; ++ks)
          acc[mi0 + m][ni0 + n] =
              __builtin_amdgcn_mfma_f32_16x16x32_bf16(af[m][ks], bf[n][ks], acc[mi0 + m][ni0 + n], 0, 0, 0);
    __builtin_amdgcn_s_setprio(0);
  };
  #define BARX() __builtin_amdgcn_s_barrier()

  // prologue: tile0 fully + A-halves of tile1 (12 loads/thread)
  stA(0, 0, 0); stA(0, 1, 0); stB(0, 0, 0); stB(0, 1, 0);
  stA(1, 0, 1); stA(1, 1, 1);
  asm volatile("s_waitcnt vmcnt(4)" ::: "memory");   // tile0 landed; Ah(1) in flight
  BARX();

  for (int j = 0; j < nk; j += 2) {
    const bool s2 = (j + 2) < nk;
    // ---- tile j (slot 0), 4 phases ----
    rdAq(0, 0, afl); rdBq(0, 0, bfl);          // P1
    stB(1, 0, j + 1);
    BARX(); quad(0, 0, afl, bfl); BARX();
    rdAq(0, 4, afh);                           // P2
    stB(1, 1, j + 1);
    BARX(); quad(4, 0, afh, bfl); BARX();
    rdBq(0, 2, bfh);                           // P3
    if (s2) stA(0, 0, j + 2);
    BARX(); quad(0, 2, afl, bfh); BARX();
    if (s2) {                                  // P4
      stA(0, 1, j + 2);
      asm volatile("s_waitcnt vmcnt(4)" ::: "memory");
    } else {
      asm volatile("s_waitcnt vmcnt(0)" ::: "memory");
    }
    BARX(); quad(4, 2, afh, bfh); BARX();
    // ---- tile j+1 (slot 1), 4 phases ----
    rdAq(1, 0, afl); rdBq(1, 0, bfl);          // P5
    if (s2) stB(0, 0, j + 2);
    BARX(); quad(0, 0, afl, bfl); BARX();
    rdAq(1, 4, afh);                           // P6
    if (s2) stB(0, 1, j + 2);
    BARX(); quad(4, 0, afh, bfl); BARX();
    rdBq(1, 2, bfh);                           // P7
    if (s2) stA(1, 0, j + 3);
    BARX(); quad(0, 2, afl, bfh); BARX();
    if (s2) {                                  // P8
      stA(1, 1, j + 3);
      asm volatile("s_waitcnt vmcnt(4)" ::: "memory");
    } else {
      asm volatile("s_waitcnt vmcnt(0)" ::: "memory");
    }
    BARX(); quad(4, 2, afh, bfh); BARX();
  }

  // epilogue: 64-row x 256-col bands (mi pairs) staged in LDS; NT stores pipeline
  float bv4[4];
  #pragma unroll
  for (int ni = 0; ni < 4; ++ni)
    bv4[ni] = bias[n0 + wn * 64 + ni * 16 + (lane & 15)];
  float* sc = (float*)As;   // 64 x 256 f32 = 64KB (full A region)
  #pragma unroll
  for (int mi2 = 0; mi2 < 8; mi2 += 2) {
    lds_barrier();
    #pragma unroll
    for (int dm = 0; dm < 2; ++dm) {
      const int mi = mi2 + dm;
      const int lr = wm * 32 + dm * 16 + (lane >> 4) * 4;
      #pragma unroll
      for (int ni = 0; ni < 4; ++ni) {
        const int lc = wn * 64 + ni * 16 + (lane & 15);
        #pragma unroll
        for (int j = 0; j < 4; ++j) {
          float v = acc[mi][ni][j] + bv4[ni];
          v = 1.f / (1.f + __expf(-v));
          sc[(lr + j) * 256 + lc] = v;
        }
      }
    }
    lds_barrier();
    #pragma unroll
    for (int u = 0; u < 8; ++u) {
      int idx = tid + u * 512;
      int r = idx >> 6, c4 = (idx & 63) * 4;
      int grow = m0 + (r >> 5) * 128 + (mi2 + ((r >> 4) & 1)) * 16 + (r & 15);
      f32x4 v4 = *(const f32x4*)(sc + r * 256 + c4);
      __builtin_nontemporal_store(v4, (f32x4*)(Cout + (size_t)grow * ldc + n0 + c4));
    }
  }
}

// ---- layer-0 aggregate via CSR (bf16 h): wave-per-row, 16B/lane, packed (idx,w) LDS
// hb row = [elu (512) | Y (16) | 0 (48)]  (ld = 576)
__global__ __launch_bounds__(256) void agg_gat0(
    const u16* __restrict__ h,
    const float* __restrict__ fs, const float* __restrict__ fd,
    const int* __restrict__ nbr, const int* __restrict__ cnt,
    const float* __restrict__ Y, u16* __restrict__ hb)
{
  __shared__ float2 np[4][CAP];
  const int tid = threadIdx.x;
  const int w = tid >> 6, lane = tid & 63;
  const int r = blockIdx.x * 4 + w;
  int c = cnt[r]; if (c > CAP) c = CAP;
  float acc[8] = {};
  const u16* hp = h + lane * 8;

  if (c > 0) {
    const float fsi = fs[r];
    float e[4];
    int jj[4];
    #pragma unroll
    for (int k = 0; k < 4; ++k) {
      int n = lane + k * 64;
      e[k] = -3.0e38f;
      if (n < c) {
        jj[k] = nbr[(size_t)r * CAP + n];
        float v = fsi + fd[jj[k]];
        e[k] = v > 0.f ? v : LRELU_ALPHA * v;
      }
    }
    float m = waveMax(fmaxf(fmaxf(e[0], e[1]), fmaxf(e[2], e[3])));
    float p[4], ps = 0.f;
    #pragma unroll
    for (int k = 0; k < 4; ++k) {
      int n = lane + k * 64;
      p[k] = (n < c) ? __expf(e[k] - m) : 0.f;
      ps += p[k];
    }
    const float inv = 1.f / waveSum(ps);
    #pragma unroll
    for (int k = 0; k < 4; ++k) {
      int n = lane + k * 64;
      if (n < c) np[w][n] = float2{__int_as_float(jj[k]), p[k] * inv};
    }
    #pragma unroll 4
    for (int n = 0; n < c; ++n) {
      float2 e2 = np[w][n];
      int j = __float_as_int(e2.x);
      float pn = e2.y;
      u16x8 hv = *(const u16x8*)(hp + (size_t)j * 512);
      #pragma unroll
      for (int q = 0; q < 8; ++q) acc[q] = fmaf(pn, bf2f(hv[q]), acc[q]);
    }
  } else {
    for (int j = 0; j < NN; ++j) {
      u16x8 hv = *(const u16x8*)(hp + (size_t)j * 512);
      #pragma unroll
      for (int q = 0; q < 8; ++q) acc[q] += bf2f(hv[q]);
    }
    #pragma unroll
    for (int q = 0; q < 8; ++q) acc[q] *= (1.f / NN);
  }
  u16x8 o;
  #pragma unroll
  for (int q = 0; q < 8; ++q) {
    float v = acc[q] > 0.f ? acc[q] : expm1f(acc[q]);
    o[q] = f2bf(v);
  }
  u16* row = hb + (size_t)r * 576;
  *(u16x8*)(row + lane * 8) = o;
  if (lane < 4) {
    float4 yv = *(const float4*)(Y + (size_t)r * 16 + 4 * lane);
    *(u16x4*)(row + 512 + 4 * lane) = u16x4{f2bf(yv.x), f2bf(yv.y), f2bf(yv.z), f2bf(yv.w)};
  } else if (lane < 16) {
    *(u16x4*)(row + 528 + 4 * (lane - 4)) = u16x4{0, 0, 0, 0};
  }
}

// ---- fused layers 1+2 aggregate + reparam + concat: wave-per-row, 16B/lane
// zcat row = [z (256) | Y (16) | 0 (48)]  (ld = 320)
__global__ __launch_bounds__(256) void agg_gat12(
    const u16* __restrict__ h12,
    const float* __restrict__ fs1, const float* __restrict__ fd1,
    const float* __restrict__ fs2, const float* __restrict__ fd2,
    const int* __restrict__ nbr, const int* __restrict__ cnt,
    const float* __restrict__ noise, const float* __restrict__ Y,
    u16* __restrict__ zcat)
{
  __shared__ float4 np[4][CAP];
  const int tid = threadIdx.x;
  const int w = tid >> 6, lane = tid & 63;
  const int r = blockIdx.x * 4 + w;
  int c = cnt[r]; if (c > CAP) c = CAP;
  float acc[8] = {};
  const u16* hp = h12 + lane * 8;

  if (c > 0) {
    const float f1 = fs1[r], f2 = fs2[r];
    float e1[4], e2[4];
    int jj[4];
    #pragma unroll
    for (int k = 0; k < 4; ++k) {
      int n = lane + k * 64;
      e1[k] = -3.0e38f; e2[k] = -3.0e38f;
      if (n < c) {
        jj[k] = nbr[(size_t)r * CAP + n];
        float v1 = f1 + fd1[jj[k]], v2 = f2 + fd2[jj[k]];
        e1[k] = v1 > 0.f ? v1 : LRELU_ALPHA * v1;
        e2[k] = v2 > 0.f ? v2 : LRELU_ALPHA * v2;
      }
    }
    float g1 = waveMax(fmaxf(fmaxf(e1[0], e1[1]), fmaxf(e1[2], e1[3])));
    float g2 = waveMax(fmaxf(fmaxf(e2[0], e2[1]), fmaxf(e2[2], e2[3])));
    float q1[4], q2[4], s1p = 0.f, s2p = 0.f;
    #pragma unroll
    for (int k = 0; k < 4; ++k) {
      int n = lane + k * 64;
      q1[k] = (n < c) ? __expf(e1[k] - g1) : 0.f;
      q2[k] = (n < c) ? __expf(e2[k] - g2) : 0.f;
      s1p += q1[k]; s2p += q2[k];
    }
    const float i1 = 1.f / waveSum(s1p);
    const float i2 = 1.f / waveSum(s2p);
    #pragma unroll
    for (int k = 0; k < 4; ++k) {
      int n = lane + k * 64;
      if (n < c) np[w][n] = float4{__int_as_float(jj[k]), q1[k] * i1, q2[k] * i2, 0.f};
    }
    const bool loHalf = (lane < 32);
    #pragma unroll 4
    for (int n = 0; n < c; ++n) {
      float4 e4 = np[w][n];
      int j = __float_as_int(e4.x);
      float pn = loHalf ? e4.y : e4.z;
      u16x8 hv = *(const u16x8*)(hp + (size_t)j * 512);
      #pragma unroll
      for (int q = 0; q < 8; ++q) acc[q] = fmaf(pn, bf2f(hv[q]), acc[q]);
    }
  } else {
    for (int j = 0; j < NN; ++j) {
      u16x8 hv = *(const u16x8*)(hp + (size_t)j * 512);
      #pragma unroll
      for (int q = 0; q < 8; ++q) acc[q] += bf2f(hv[q]);
    }
    #pragma unroll
    for (int q = 0; q < 8; ++q) acc[q] *= (1.f / NN);
  }
  // ELU
  float v[8];
  #pragma unroll
  for (int q = 0; q < 8; ++q) v[q] = acc[q] > 0.f ? acc[q] : expm1f(acc[q]);
  // lsd values live in lane+32; pull down for reparam
  float lsd[8];
  #pragma unroll
  for (int q = 0; q < 8; ++q) lsd[q] = __shfl_xor(v[q], 32, 64);
  u16* row = zcat + (size_t)r * 320;
  if (lane < 32) {
    const float* nz = noise + (size_t)r * 256 + lane * 8;
    float4 na = *(const float4*)nz, nbv = *(const float4*)(nz + 4);
    float nzv[8] = {na.x, na.y, na.z, na.w, nbv.x, nbv.y, nbv.z, nbv.w};
    u16x8 o;
    #pragma unroll
    for (int q = 0; q < 8; ++q)
      o[q] = f2bf(fmaf(nzv[q], __expf(lsd[q]), v[q]));
    *(u16x8*)(row + lane * 8) = o;
  } else if (lane < 36) {
    float4 yv = *(const float4*)(Y + (size_t)r * 16 + 4 * (lane - 32));
    *(u16x4*)(row + 256 + 4 * (lane - 32)) = u16x4{f2bf(yv.x), f2bf(yv.y), f2bf(yv.z), f2bf(yv.w)};
  } else if (lane < 48) {
    *(u16x4*)(row + 272 + 4 * (lane - 36)) = u16x4{0, 0, 0, 0};
  }
}

extern "C" void kernel_launch(void* const* d_in, const int* in_sizes, int n_in,
                              void* d_out, int out_size, void* d_ws, size_t ws_size,
                              hipStream_t stream)
{
  const float* X     = (const float*)d_in[0];
  const float* Y     = (const float*)d_in[1];
  const float* noise = (const float*)d_in[2];
  const void*  adj   = d_in[3];
  const float* W0    = (const float*)d_in[4];
  const float* a0    = (const float*)d_in[5];
  const float* W1    = (const float*)d_in[6];
  const float* a1    = (const float*)d_in[7];
  const float* W2    = (const float*)d_in[8];
  const float* a2    = (const float*)d_in[9];
  const float* fc1w  = (const float*)d_in[10];
  const float* fc1b  = (const float*)d_in[11];
  const float* fc2w  = (const float*)d_in[12];
  const float* fc2b  = (const float*)d_in[13];
  float* out = (float*)d_out;
  char* W = (char*)d_ws;

  // workspace layout (bytes), ~27.8 MB
  u16*   Xb    = (u16*)(W + 0);            // 4096x1024 bf16 (dead after gemm0)
  u16*   zcatb = (u16*)(W + 0);            // 4096x320 bf16
  u16*   zzb   = (u16*)(W + 2621440);      // 4096x512 bf16
  u16*   h0b   = (u16*)(W + 8388608);      // 4096x512 bf16 (dead after agg0)
  u16*   h12b  = (u16*)(W + 8388608);      // 4096x512 bf16 (reuses h0b region)
  u16*   hb    = (u16*)(W + 12582912);     // 4096x576 bf16
  u16*   W0t   = (u16*)(W + 17301504);     // 512x1024
  u16*   W12t  = (u16*)(W + 18350080);     // 512x576
  u16*   fc1t  = (u16*)(W + 18939904);     // 512x320
  u16*   fc2t  = (u16*)(W + 19267584);     // 4096x512
  int*   nbr   = (int*)(W + 23461888);     // 4096x256 int
  int*   cnt   = (int*)(W + 27656192);     // 4096 int
  float* fs0   = (float*)(W + 27672576);   // fs0,fd0,fs1,fd1,fs2,fd2 contiguous
  float* fd0   = fs0 + 4096;
  float* fs1   = fd0 + 4096;
  float* fd1   = fs1 + 4096;
  float* fs2   = fd1 + 4096;
  float* fd2   = fs2 + 4096;

  // 1) dedicated CSR scan (full occupancy, HBM-bound)
  build_csr<<<4096, 256, 0, stream>>>((const unsigned*)adj, nbr, cnt);

  // 2) transposes (incl fc2) + X convert + fs/fd zero
  prep_all<<<7128, 256, 0, stream>>>(W0, W0t, W1, W12t, W2, W12t + 256 * 576,
                                     fc1w, fc1t, fc2w, fc2t, X, Xb, fs0);

  // 3) gemm0 (+fused fsrc0 atomics), K=1024
  gemm_mfma64<0, true, 1><<<dim3(8, 32), 256, 0, stream>>>(
      Xb, 1024, W0t, 1024, h0b, 512, 1024, nullptr, a0, nullptr, fs0, fd0, nullptr, nullptr);

  // 4) layer-0 aggregate
  agg_gat0<<<1024, 256, 0, stream>>>(h0b, fs0, fd0, nbr, cnt, Y, hb);

  // 5) layers 1&2 GEMM (+fused fsrc12 atomics), K=576
  gemm_mfma64<0, true, 2><<<dim3(8, 32), 256, 0, stream>>>(
      hb, 576, W12t, 576, h12b, 512, 576, nullptr, a1, a2, fs1, fd1, fs2, fd2);

  // 6) layers 1&2 aggregate + reparam + concat
  agg_gat12<<<1024, 256, 0, stream>>>(h12b, fs1, fd1, fs2, fd2, nbr, cnt, noise, Y, zcatb);

  // 7) decoder fc1, K=320
  gemm_mfma64<1, true, 0><<<dim3(8, 32), 256, 0, stream>>>(
      zcatb, 320, fc1t, 320, zzb, 512, 320, fc1b,
      nullptr, nullptr, nullptr, nullptr, nullptr, nullptr);

  // 8) decoder fc2, K=512
  gemm_fc2_8p<<<dim3(16, 16), 512, 0, stream>>>(zzb, 512, fc2t, 512, out, 4096, 512, fc2b);
}

// Round 20
// 111.063 us; speedup vs baseline: 1.0540x; 1.0540x over previous
//
#include <hip/hip_runtime.h>

#define LRELU_ALPHA 0.2f
#define NN 4096
#define CAP 256

typedef unsigned short u16;
typedef short bf16x8 __attribute__((ext_vector_type(8)));
typedef float f32x4 __attribute__((ext_vector_type(4)));
typedef u16 u16x4 __attribute__((ext_vector_type(4)));
typedef u16 u16x2 __attribute__((ext_vector_type(2)));
typedef u16 u16x8 __attribute__((ext_vector_type(8)));

__device__ __forceinline__ u16 f2bf(float f) {
  unsigned u = __float_as_uint(f);
  u += 0x7FFFu + ((u >> 16) & 1u);
  return (u16)(u >> 16);
}
__device__ __forceinline__ float bf2f(u16 u) {
  return __uint_as_float(((unsigned)u) << 16);
}

// butterfly reductions: result valid in ALL 64 lanes
__device__ __forceinline__ float waveSum(float v) {
  #pragma unroll
  for (int o = 32; o > 0; o >>= 1) v += __shfl_xor(v, o, 64);
  return v;
}
__device__ __forceinline__ float waveMax(float v) {
  #pragma unroll
  for (int o = 32; o > 0; o >>= 1) v = fmaxf(v, __shfl_xor(v, o, 64));
  return v;
}

__device__ __forceinline__ void gload_lds16(const void* g, void* l) {
  __builtin_amdgcn_global_load_lds((const __attribute__((address_space(1))) void*)g,
                                   (__attribute__((address_space(3))) void*)l, 16, 0, 0);
}

// LDS-only barrier (no vmcnt drain): epilogue global stores keep flying
__device__ __forceinline__ void lds_barrier() {
  asm volatile("s_waitcnt lgkmcnt(0)" ::: "memory");
  __builtin_amdgcn_s_barrier();
}

// ---- CSR build body: one block per row, wave-local shfl scan + 4-entry combine
__device__ __forceinline__ void csr_body(const unsigned* __restrict__ adjw,
                                         int* __restrict__ nbr, int* __restrict__ cnt,
                                         int i, int* wsum)
{
  const int tid = threadIdx.x;
  const int w = tid >> 6, lane = tid & 63;
  unsigned bits = 0;
  const unsigned* row = adjw + (size_t)i * 4096 + tid * 16;
  #pragma unroll
  for (int ck = 0; ck < 4; ++ck) {
    uint4 v = *(const uint4*)(row + ck * 4);
    if (v.x) bits |= 1u << (ck * 4 + 0);
    if (v.y) bits |= 1u << (ck * 4 + 1);
    if (v.z) bits |= 1u << (ck * 4 + 2);
    if (v.w) bits |= 1u << (ck * 4 + 3);
  }
  int mycnt = __popc(bits);
  int incl = mycnt;
  #pragma unroll
  for (int o = 1; o < 64; o <<= 1) {
    int v = __shfl_up(incl, o, 64);
    if (lane >= o) incl += v;
  }
  if (lane == 63) wsum[w] = incl;
  __syncthreads();
  int base = 0;
  #pragma unroll
  for (int k = 0; k < 4; ++k) base += (k < w) ? wsum[k] : 0;
  const int total = wsum[0] + wsum[1] + wsum[2] + wsum[3];
  int pos = base + incl - mycnt;
  #pragma unroll
  for (int b = 0; b < 16; ++b) {
    if (bits & (1u << b)) {
      if (pos < CAP) nbr[(size_t)i * CAP + pos] = tid * 16 + b;
      ++pos;
    }
  }
  if (tid == 0) cnt[i] = total;
}

// ---- transpose helper (flat 256 threads): Wt[n][k] (bf16, ld=Kpad) from W[k][n] (f32)
__device__ __forceinline__ void transpose_body(const float* Wsrc, u16* Wt,
                                               int K, int N, int Kpad,
                                               int bx, int by, float (*t)[33]) {
  const int kb = by * 32, nb = bx * 32;
  const int tx = threadIdx.x & 31, ty = threadIdx.x >> 5;  // 32 x 8
  for (int i = ty; i < 32; i += 8) {
    int k = kb + i, n = nb + tx;
    t[i][tx] = (k < K && n < N) ? Wsrc[(size_t)k * N + n] : 0.f;
  }
  __syncthreads();
  for (int i = ty; i < 32; i += 8) {
    int n = nb + i, k = kb + tx;
    if (n < N && k < Kpad) Wt[(size_t)n * Kpad + k] = f2bf(t[tx][i]);
  }
}

// ---- small weight transposes + X f32->bf16 + fs/fd zero
// [0,512) W0 | [512,656) W1 | [656,800) W2 | [800,960) fc1 | [960,5056) X | [5056,5080) zero
__global__ __launch_bounds__(256) void prep_all(
    const float* __restrict__ W0, u16* __restrict__ W0t,
    const float* __restrict__ W1, u16* __restrict__ W1t,
    const float* __restrict__ W2, u16* __restrict__ W2t,
    const float* __restrict__ fc1w, u16* __restrict__ fc1t,
    const float* __restrict__ X, u16* __restrict__ Xb,
    float* __restrict__ fsz)
{
  __shared__ float t[32][33];
  const int i = blockIdx.x, tid = threadIdx.x;
  if (i < 512) {
    transpose_body(W0, W0t, 1024, 512, 1024, i & 15, i >> 4, t);
  } else if (i < 656) {
    int j = i - 512;   // 8 x 18
    transpose_body(W1, W1t, 528, 256, 576, j & 7, j >> 3, t);
  } else if (i < 800) {
    int j = i - 656;
    transpose_body(W2, W2t, 528, 256, 576, j & 7, j >> 3, t);
  } else if (i < 960) {
    int j = i - 800;   // 16 x 10
    transpose_body(fc1w, fc1t, 272, 512, 320, j & 15, j >> 4, t);
  } else if (i < 5056) {
    int j = i - 960;
    int idx = j * 256 + tid;
    float4 v = ((const float4*)X)[idx];
    u16x4 o = {f2bf(v.x), f2bf(v.y), f2bf(v.z), f2bf(v.w)};
    ((u16x4*)Xb)[idx] = o;
  } else {
    int j = i - 5056;   // zero fs0..fd2: 6*4096 f32 = 6144 float4
    ((f32x4*)fsz)[j * 256 + tid] = f32x4{0.f, 0.f, 0.f, 0.f};
  }
}

// ---- bf16 MFMA GEMM 128x64 tile, BK=64, dbuf + counted vmcnt, pipelined epilogue,
//      XCD swizzle, optional fused attention-score reduction (atomicAdd into fs/fd).
// FS: 0 = none; 1 = single (aA[0:512]=src,[512:1024]=dst -> fsA/fdA);
//     2 = dual halves (cols<256: aA/fsA/fdA, cols>=256: aB/fsB/fdB; a layout [0:256|256:512])
template<int ACT, bool OBF, int FS>
__device__ __forceinline__ void gemm64_dev(
    const u16* __restrict__ A, int lda,
    const u16* __restrict__ Bt, int ldb,
    void* __restrict__ Cout, int ldc,
    int K, const float* __restrict__ bias,
    u16 (&As)[2][128 * 64], u16 (&Bs)[2][64 * 64], int bid,
    const float* aA, const float* aB,
    float* fsA, float* fdA, float* fsB, float* fdB)
{
  const int tid = threadIdx.x;
  const int lane = tid & 63, wv = tid >> 6;
  const int wm = wv >> 1, wn = wv & 1;
  const int swz = ((bid & 7) << 5) | (bid >> 3);
  const int m0 = (swz >> 3) * 128, n0 = (swz & 7) * 64;
  const int nk = K >> 6;

  f32x4 acc[4][2] = {};

  auto STAGE = [&](int buf, int kt) {   // 6 loads/thread
    #pragma unroll
    for (int i = 0; i < 4; ++i) {       // A: 128 rows x 8 slots
      int c = tid + i * 256;
      int r = c >> 3, sl = c & 7;
      int sg = sl ^ (r & 7);
      gload_lds16(A + (size_t)(m0 + r) * lda + kt * 64 + sg * 8, (char*)As[buf] + (c & ~63) * 16);
    }
    #pragma unroll
    for (int i = 0; i < 2; ++i) {       // B: 64 rows x 8 slots
      int c = tid + i * 256;
      int r = c >> 3, sl = c & 7;
      int sg = sl ^ (r & 7);
      gload_lds16(Bt + (size_t)(n0 + r) * ldb + kt * 64 + sg * 8, (char*)Bs[buf] + (c & ~63) * 16);
    }
  };

  STAGE(0, 0);
  if (nk > 1) STAGE(1, 1);

  int cur = 0;
  for (int kt = 0; kt < nk; ++kt) {
    if (kt + 1 < nk) { asm volatile("s_waitcnt vmcnt(6)" ::: "memory"); }
    else             { asm volatile("s_waitcnt vmcnt(0)" ::: "memory"); }
    __builtin_amdgcn_s_barrier();

    #pragma unroll
    for (int ks = 0; ks < 2; ++ks) {
      bf16x8 af[4], bf_[2];
      #pragma unroll
      for (int mi = 0; mi < 4; ++mi) {
        int r = wm * 64 + mi * 16 + (lane & 15);
        int sl = (ks * 4 + (lane >> 4)) ^ (r & 7);
        af[mi] = *(const bf16x8*)((const char*)As[cur] + r * 128 + sl * 16);
      }
      #pragma unroll
      for (int ni = 0; ni < 2; ++ni) {
        int r = wn * 32 + ni * 16 + (lane & 15);
        int sl = (ks * 4 + (lane >> 4)) ^ (r & 7);
        bf_[ni] = *(const bf16x8*)((const char*)Bs[cur] + r * 128 + sl * 16);
      }
      __builtin_amdgcn_s_setprio(1);
      #pragma unroll
      for (int mi = 0; mi < 4; ++mi)
        #pragma unroll
        for (int ni = 0; ni < 2; ++ni)
          acc[mi][ni] = __builtin_amdgcn_mfma_f32_16x16x32_bf16(af[mi], bf_[ni], acc[mi][ni], 0, 0, 0);
      __builtin_amdgcn_s_setprio(0);
    }

    __builtin_amdgcn_s_barrier();
    if (kt + 2 < nk) STAGE(cur, kt + 2);
    cur ^= 1;
  }

  float bv2[2];
  #pragma unroll
  for (int ni = 0; ni < 2; ++ni)
    bv2[ni] = bias ? bias[n0 + wn * 32 + ni * 16 + (lane & 15)] : 0.f;
  float* sc = (float*)As;
  #pragma unroll
  for (int mi = 0; mi < 4; ++mi) {
    lds_barrier();
    const int lr = wm * 16 + (lane >> 4) * 4;
    #pragma unroll
    for (int ni = 0; ni < 2; ++ni) {
      const int lc = wn * 32 + ni * 16 + (lane & 15);
      #pragma unroll
      for (int j = 0; j < 4; ++j) {
        float v = acc[mi][ni][j] + bv2[ni];
        if (ACT == 1) v = fmaxf(v, 0.f);
        if (ACT == 2) v = 1.f / (1.f + __expf(-v));
        sc[(lr + j) * 64 + lc] = v;
      }
    }
    lds_barrier();
    // fused attention-score partials from the staged f32 band
    if constexpr (FS > 0) {
      const float* aS; const float* aD; float* fsO; float* fdO; int colbase;
      if constexpr (FS == 1) {
        aS = aA; aD = aA + 512; fsO = fsA; fdO = fdA; colbase = n0;
      } else {
        const bool lo2 = (n0 < 256);
        const float* av = lo2 ? aA : aB;
        aS = av; aD = av + 256;
        fsO = lo2 ? fsA : fsB; fdO = lo2 ? fdA : fdB;
        colbase = n0 & 255;
      }
      const int rr = tid >> 3, cg = tid & 7;
      float s0 = 0.f, s1 = 0.f;
      #pragma unroll
      for (int q = 0; q < 8; ++q) {
        float hv = sc[rr * 64 + cg * 8 + q];
        s0 = fmaf(hv, aS[colbase + cg * 8 + q], s0);
        s1 = fmaf(hv, aD[colbase + cg * 8 + q], s1);
      }
      #pragma unroll
      for (int o = 1; o < 8; o <<= 1) {
        s0 += __shfl_xor(s0, o, 64);
        s1 += __shfl_xor(s1, o, 64);
      }
      if (cg == 0) {
        int grow = m0 + (rr >> 4) * 64 + mi * 16 + (rr & 15);
        atomicAdd(fsO + grow, s0);
        atomicAdd(fdO + grow, s1);
      }
    }
    #pragma unroll
    for (int u = 0; u < 2; ++u) {
      int idx = tid + u * 256;
      int r = idx >> 4, c4 = (idx & 15) * 4;
      int grow = m0 + (r >> 4) * 64 + mi * 16 + (r & 15);
      float4 v4 = *(const float4*)(sc + r * 64 + c4);
      if (OBF) {
        u16x4 o = {f2bf(v4.x), f2bf(v4.y), f2bf(v4.z), f2bf(v4.w)};
        *(u16x4*)((u16*)Cout + (size_t)grow * ldc + n0 + c4) = o;
      } else {
        *(float4*)((float*)Cout + (size_t)grow * ldc + n0 + c4) = v4;
      }
    }
  }
}

template<int ACT, bool OBF, int FS>
__global__ __launch_bounds__(256) void gemm_mfma64(
    const u16* __restrict__ A, int lda, const u16* __restrict__ Bt, int ldb,
    void* __restrict__ Cout, int ldc, int K, const float* __restrict__ bias,
    const float* aA, const float* aB,
    float* fsA, float* fdA, float* fsB, float* fdB)
{
  __shared__ u16 As[2][128 * 64];
  __shared__ u16 Bs[2][64 * 64];
  gemm64_dev<ACT, OBF, FS>(A, lda, Bt, ldb, Cout, ldc, K, bias, As, Bs,
                           blockIdx.y * 8 + blockIdx.x, aA, aB, fsA, fdA, fsB, fdB);
}

// ---- merged dispatch (R17 structure, measured best):
// [0,256) gemm0+fsrc0 | [256,4352) build_csr (wave-scan) | [4352,6400) fc2 transpose
__global__ __launch_bounds__(256) void csr_gemm0(
    const u16* __restrict__ Xb, const u16* __restrict__ W0t, u16* __restrict__ h0b,
    const unsigned* __restrict__ adjw,
    int* __restrict__ nbr, int* __restrict__ cnt,
    const float* __restrict__ fc2w, u16* __restrict__ fc2t,
    const float* __restrict__ a0, float* __restrict__ fs0, float* __restrict__ fd0)
{
  __shared__ u16 As[2][128 * 64];
  __shared__ u16 Bs[2][64 * 64];
  if (blockIdx.x < 256) {
    gemm64_dev<0, true, 1>(Xb, 1024, W0t, 1024, h0b, 512, 1024, nullptr, As, Bs, blockIdx.x,
                           a0, nullptr, fs0, fd0, nullptr, nullptr);
  } else if (blockIdx.x < 4352) {
    csr_body(adjw, nbr, cnt, blockIdx.x - 256, (int*)As);
  } else {
    int j = blockIdx.x - 4352;   // fc2: K=512 (16 k-tiles) x N=4096 (128 n-tiles)
    transpose_body(fc2w, fc2t, 512, 4096, 512, j & 127, j >> 7, (float(*)[33])As);
  }
}

// ---- fc2: 256x256 tile, BK=64, 8 waves, 8-PHASE counted-vmcnt schedule,
//      pipelined staged NT epilogue (64-row bands), XCD swizzle. K even*64.
__global__ __launch_bounds__(512, 2) void gemm_fc2_8p(
    const u16* __restrict__ A, int lda,
    const u16* __restrict__ Bt, int ldb,
    float* __restrict__ Cout, int ldc,
    int K, const float* __restrict__ bias)
{
  __shared__ u16 As[2][2][128 * 64];   // [slot][half] 16KB each -> 64KB
  __shared__ u16 Bs[2][2][128 * 64];   // 64KB
  const int tid = threadIdx.x;
  const int lane = tid & 63, wv = tid >> 6;
  const int wm = wv >> 2, wn = wv & 3;          // 2 x 4; wave owns 128x64
  const int bid = blockIdx.y * 16 + blockIdx.x;
  const int swz = ((bid & 7) << 5) | (bid >> 3);
  const int m0 = (swz >> 4) * 256, n0 = (swz & 15) * 256;
  const int nk = K >> 6;

  f32x4 acc[8][4] = {};

  auto stA = [&](int slot, int h, int t) {      // 2 loads/thread (one 128x64 half)
    const u16* Ap = A + (size_t)(m0 + h * 128) * lda + t * 64;
    #pragma unroll
    for (int i = 0; i < 2; ++i) {
      int c = tid + i * 512;
      int r = c >> 3, sl = c & 7;
      int sg = sl ^ (r & 7);
      gload_lds16(Ap + (size_t)r * lda + sg * 8, (char*)&As[slot][h][0] + (c & ~63) * 16);
    }
  };
  auto stB = [&](int slot, int h, int t) {
    const u16* Bp = Bt + (size_t)(n0 + h * 128) * ldb + t * 64;
    #pragma unroll
    for (int i = 0; i < 2; ++i) {
      int c = tid + i * 512;
      int r = c >> 3, sl = c & 7;
      int sg = sl ^ (r & 7);
      gload_lds16(Bp + (size_t)r * ldb + sg * 8, (char*)&Bs[slot][h][0] + (c & ~63) * 16);
    }
  };

  bf16x8 afl[4][2], afh[4][2], bfl[2][2], bfh[2][2];
  auto rdAq = [&](int slot, int mi0, bf16x8 (&dst)[4][2]) {
    #pragma unroll
    for (int m = 0; m < 4; ++m)
      #pragma unroll
      for (int ks = 0; ks < 2; ++ks) {
        int r = (mi0 + m) * 16 + (lane & 15);
        int sl = (ks * 4 + (lane >> 4)) ^ (r & 7);
        dst[m][ks] = *(const bf16x8*)((const char*)&As[slot][wm][0] + r * 128 + sl * 16);
      }
  };
  auto rdBq = [&](int slot, int ni0, bf16x8 (&dst)[2][2]) {
    #pragma unroll
    for (int n = 0; n < 2; ++n)
      #pragma unroll
      for (int ks = 0; ks < 2; ++ks) {
        int r = (wn & 1) * 64 + (ni0 + n) * 16 + (lane & 15);
        int sl = (ks * 4 + (lane >> 4)) ^ (r & 7);
        dst[n][ks] = *(const bf16x8*)((const char*)&Bs[slot][wn >> 1][0] + r * 128 + sl * 16);
      }
  };
  auto quad = [&](int mi0, int ni0, bf16x8 (&af)[4][2], bf16x8 (&bf)[2][2]) {
    __builtin_amdgcn_s_setprio(1);
    #pragma unroll
    for (int m = 0; m < 4; ++m)
      #pragma unroll
      for (int n = 0; n < 2; ++n)
        #pragma unroll
        for (int ks = 0; ks < 2; ++ks)
          acc[mi0 + m][ni0 + n] =
              __builtin_amdgcn_mfma_f32_16x16x32_bf16(af[m][ks], bf[n][ks], acc[mi0 + m][ni0 + n], 0, 0, 0);
    __builtin_amdgcn_s_setprio(0);
  };
  #define BARX() __builtin_amdgcn_s_barrier()

  // prologue: tile0 fully + A-halves of tile1 (12 loads/thread)
  stA(0, 0, 0); stA(0, 1, 0); stB(0, 0, 0); stB(0, 1, 0);
  stA(1, 0, 1); stA(1, 1, 1);
  asm volatile("s_waitcnt vmcnt(4)" ::: "memory");   // tile0 landed; Ah(1) in flight
  BARX();

  for (int j = 0; j < nk; j += 2) {
    const bool s2 = (j + 2) < nk;
    // ---- tile j (slot 0), 4 phases ----
    rdAq(0, 0, afl); rdBq(0, 0, bfl);          // P1
    stB(1, 0, j + 1);
    BARX(); quad(0, 0, afl, bfl); BARX();
    rdAq(0, 4, afh);                           // P2
    stB(1, 1, j + 1);
    BARX(); quad(4, 0, afh, bfl); BARX();
    rdBq(0, 2, bfh);                           // P3
    if (s2) stA(0, 0, j + 2);
    BARX(); quad(0, 2, afl, bfh); BARX();
    if (s2) {                                  // P4
      stA(0, 1, j + 2);
      asm volatile("s_waitcnt vmcnt(4)" ::: "memory");
    } else {
      asm volatile("s_waitcnt vmcnt(0)" ::: "memory");
    }
    BARX(); quad(4, 2, afh, bfh); BARX();
    // ---- tile j+1 (slot 1), 4 phases ----
    rdAq(1, 0, afl); rdBq(1, 0, bfl);          // P5
    if (s2) stB(0, 0, j + 2);
    BARX(); quad(0, 0, afl, bfl); BARX();
    rdAq(1, 4, afh);                           // P6
    if (s2) stB(0, 1, j + 2);
    BARX(); quad(4, 0, afh, bfl); BARX();
    rdBq(1, 2, bfh);                           // P7
    if (s2) stA(1, 0, j + 3);
    BARX(); quad(0, 2, afl, bfh); BARX();
    if (s2) {                                  // P8
      stA(1, 1, j + 3);
      asm volatile("s_waitcnt vmcnt(4)" ::: "memory");
    } else {
      asm volatile("s_waitcnt vmcnt(0)" ::: "memory");
    }
    BARX(); quad(4, 2, afh, bfh); BARX();
  }

  // epilogue: 64-row x 256-col bands (mi pairs) staged in LDS; NT stores pipeline
  float bv4[4];
  #pragma unroll
  for (int ni = 0; ni < 4; ++ni)
    bv4[ni] = bias[n0 + wn * 64 + ni * 16 + (lane & 15)];
  float* sc = (float*)As;   // 64 x 256 f32 = 64KB (full A region)
  #pragma unroll
  for (int mi2 = 0; mi2 < 8; mi2 += 2) {
    lds_barrier();
    #pragma unroll
    for (int dm = 0; dm < 2; ++dm) {
      const int mi = mi2 + dm;
      const int lr = wm * 32 + dm * 16 + (lane >> 4) * 4;
      #pragma unroll
      for (int ni = 0; ni < 4; ++ni) {
        const int lc = wn * 64 + ni * 16 + (lane & 15);
        #pragma unroll
        for (int j = 0; j < 4; ++j) {
          float v = acc[mi][ni][j] + bv4[ni];
          v = 1.f / (1.f + __expf(-v));
          sc[(lr + j) * 256 + lc] = v;
        }
      }
    }
    lds_barrier();
    #pragma unroll
    for (int u = 0; u < 8; ++u) {
      int idx = tid + u * 512;
      int r = idx >> 6, c4 = (idx & 63) * 4;
      int grow = m0 + (r >> 5) * 128 + (mi2 + ((r >> 4) & 1)) * 16 + (r & 15);
      f32x4 v4 = *(const f32x4*)(sc + r * 256 + c4);
      __builtin_nontemporal_store(v4, (f32x4*)(Cout + (size_t)grow * ldc + n0 + c4));
    }
  }
}

// ---- layer-0 aggregate via CSR (bf16 h): wave-per-row, 16B/lane, packed (idx,w) LDS
// hb row = [elu (512) | Y (16) | 0 (48)]  (ld = 576)
__global__ __launch_bounds__(256) void agg_gat0(
    const u16* __restrict__ h,
    const float* __restrict__ fs, const float* __restrict__ fd,
    const int* __restrict__ nbr, const int* __restrict__ cnt,
    const float* __restrict__ Y, u16* __restrict__ hb)
{
  __shared__ float2 np[4][CAP];
  const int tid = threadIdx.x;
  const int w = tid >> 6, lane = tid & 63;
  const int r = blockIdx.x * 4 + w;
  int c = cnt[r]; if (c > CAP) c = CAP;
  float acc[8] = {};
  const u16* hp = h + lane * 8;

  if (c > 0) {
    const float fsi = fs[r];
    float e[4];
    int jj[4];
    #pragma unroll
    for (int k = 0; k < 4; ++k) {
      int n = lane + k * 64;
      e[k] = -3.0e38f;
      if (n < c) {
        jj[k] = nbr[(size_t)r * CAP + n];
        float v = fsi + fd[jj[k]];
        e[k] = v > 0.f ? v : LRELU_ALPHA * v;
      }
    }
    float m = waveMax(fmaxf(fmaxf(e[0], e[1]), fmaxf(e[2], e[3])));
    float p[4], ps = 0.f;
    #pragma unroll
    for (int k = 0; k < 4; ++k) {
      int n = lane + k * 64;
      p[k] = (n < c) ? __expf(e[k] - m) : 0.f;
      ps += p[k];
    }
    const float inv = 1.f / waveSum(ps);
    #pragma unroll
    for (int k = 0; k < 4; ++k) {
      int n = lane + k * 64;
      if (n < c) np[w][n] = float2{__int_as_float(jj[k]), p[k] * inv};
    }
    #pragma unroll 4
    for (int n = 0; n < c; ++n) {
      float2 e2 = np[w][n];
      int j = __float_as_int(e2.x);
      float pn = e2.y;
      u16x8 hv = *(const u16x8*)(hp + (size_t)j * 512);
      #pragma unroll
      for (int q = 0; q < 8; ++q) acc[q] = fmaf(pn, bf2f(hv[q]), acc[q]);
    }
  } else {
    for (int j = 0; j < NN; ++j) {
      u16x8 hv = *(const u16x8*)(hp + (size_t)j * 512);
      #pragma unroll
      for (int q = 0; q < 8; ++q) acc[q] += bf2f(hv[q]);
    }
    #pragma unroll
    for (int q = 0; q < 8; ++q) acc[q] *= (1.f / NN);
  }
  u16x8 o;
  #pragma unroll
  for (int q = 0; q < 8; ++q) {
    float v = acc[q] > 0.f ? acc[q] : expm1f(acc[q]);
    o[q] = f2bf(v);
  }
  u16* row = hb + (size_t)r * 576;
  *(u16x8*)(row + lane * 8) = o;
  if (lane < 4) {
    float4 yv = *(const float4*)(Y + (size_t)r * 16 + 4 * lane);
    *(u16x4*)(row + 512 + 4 * lane) = u16x4{f2bf(yv.x), f2bf(yv.y), f2bf(yv.z), f2bf(yv.w)};
  } else if (lane < 16) {
    *(u16x4*)(row + 528 + 4 * (lane - 4)) = u16x4{0, 0, 0, 0};
  }
}

// ---- fused layers 1+2 aggregate + reparam + concat: wave-per-row, 16B/lane
// zcat row = [z (256) | Y (16) | 0 (48)]  (ld = 320)
__global__ __launch_bounds__(256) void agg_gat12(
    const u16* __restrict__ h12,
    const float* __restrict__ fs1, const float* __restrict__ fd1,
    const float* __restrict__ fs2, const float* __restrict__ fd2,
    const int* __restrict__ nbr, const int* __restrict__ cnt,
    const float* __restrict__ noise, const float* __restrict__ Y,
    u16* __restrict__ zcat)
{
  __shared__ float4 np[4][CAP];
  const int tid = threadIdx.x;
  const int w = tid >> 6, lane = tid & 63;
  const int r = blockIdx.x * 4 + w;
  int c = cnt[r]; if (c > CAP) c = CAP;
  float acc[8] = {};
  const u16* hp = h12 + lane * 8;

  if (c > 0) {
    const float f1 = fs1[r], f2 = fs2[r];
    float e1[4], e2[4];
    int jj[4];
    #pragma unroll
    for (int k = 0; k < 4; ++k) {
      int n = lane + k * 64;
      e1[k] = -3.0e38f; e2[k] = -3.0e38f;
      if (n < c) {
        jj[k] = nbr[(size_t)r * CAP + n];
        float v1 = f1 + fd1[jj[k]], v2 = f2 + fd2[jj[k]];
        e1[k] = v1 > 0.f ? v1 : LRELU_ALPHA * v1;
        e2[k] = v2 > 0.f ? v2 : LRELU_ALPHA * v2;
      }
    }
    float g1 = waveMax(fmaxf(fmaxf(e1[0], e1[1]), fmaxf(e1[2], e1[3])));
    float g2 = waveMax(fmaxf(fmaxf(e2[0], e2[1]), fmaxf(e2[2], e2[3])));
    float q1[4], q2[4], s1p = 0.f, s2p = 0.f;
    #pragma unroll
    for (int k = 0; k < 4; ++k) {
      int n = lane + k * 64;
      q1[k] = (n < c) ? __expf(e1[k] - g1) : 0.f;
      q2[k] = (n < c) ? __expf(e2[k] - g2) : 0.f;
      s1p += q1[k]; s2p += q2[k];
    }
    const float i1 = 1.f / waveSum(s1p);
    const float i2 = 1.f / waveSum(s2p);
    #pragma unroll
    for (int k = 0; k < 4; ++k) {
      int n = lane + k * 64;
      if (n < c) np[w][n] = float4{__int_as_float(jj[k]), q1[k] * i1, q2[k] * i2, 0.f};
    }
    const bool loHalf = (lane < 32);
    #pragma unroll 4
    for (int n = 0; n < c; ++n) {
      float4 e4 = np[w][n];
      int j = __float_as_int(e4.x);
      float pn = loHalf ? e4.y : e4.z;
      u16x8 hv = *(const u16x8*)(hp + (size_t)j * 512);
      #pragma unroll
      for (int q = 0; q < 8; ++q) acc[q] = fmaf(pn, bf2f(hv[q]), acc[q]);
    }
  } else {
    for (int j = 0; j < NN; ++j) {
      u16x8 hv = *(const u16x8*)(hp + (size_t)j * 512);
      #pragma unroll
      for (int q = 0; q < 8; ++q) acc[q] += bf2f(hv[q]);
    }
    #pragma unroll
    for (int q = 0; q < 8; ++q) acc[q] *= (1.f / NN);
  }
  // ELU
  float v[8];
  #pragma unroll
  for (int q = 0; q < 8; ++q) v[q] = acc[q] > 0.f ? acc[q] : expm1f(acc[q]);
  // lsd values live in lane+32; pull down for reparam
  float lsd[8];
  #pragma unroll
  for (int q = 0; q < 8; ++q) lsd[q] = __shfl_xor(v[q], 32, 64);
  u16* row = zcat + (size_t)r * 320;
  if (lane < 32) {
    const float* nz = noise + (size_t)r * 256 + lane * 8;
    float4 na = *(const float4*)nz, nbv = *(const float4*)(nz + 4);
    float nzv[8] = {na.x, na.y, na.z, na.w, nbv.x, nbv.y, nbv.z, nbv.w};
    u16x8 o;
    #pragma unroll
    for (int q = 0; q < 8; ++q)
      o[q] = f2bf(fmaf(nzv[q], __expf(lsd[q]), v[q]));
    *(u16x8*)(row + lane * 8) = o;
  } else if (lane < 36) {
    float4 yv = *(const float4*)(Y + (size_t)r * 16 + 4 * (lane - 32));
    *(u16x4*)(row + 256 + 4 * (lane - 32)) = u16x4{f2bf(yv.x), f2bf(yv.y), f2bf(yv.z), f2bf(yv.w)};
  } else if (lane < 48) {
    *(u16x4*)(row + 272 + 4 * (lane - 36)) = u16x4{0, 0, 0, 0};
  }
}

extern "C" void kernel_launch(void* const* d_in, const int* in_sizes, int n_in,
                              void* d_out, int out_size, void* d_ws, size_t ws_size,
                              hipStream_t stream)
{
  const float* X     = (const float*)d_in[0];
  const float* Y     = (const float*)d_in[1];
  const float* noise = (const float*)d_in[2];
  const void*  adj   = d_in[3];
  const float* W0    = (const float*)d_in[4];
  const float* a0    = (const float*)d_in[5];
  const float* W1    = (const float*)d_in[6];
  const float* a1    = (const float*)d_in[7];
  const float* W2    = (const float*)d_in[8];
  const float* a2    = (const float*)d_in[9];
  const float* fc1w  = (const float*)d_in[10];
  const float* fc1b  = (const float*)d_in[11];
  const float* fc2w  = (const float*)d_in[12];
  const float* fc2b  = (const float*)d_in[13];
  float* out = (float*)d_out;
  char* W = (char*)d_ws;

  // workspace layout (bytes), ~27.8 MB
  u16*   Xb    = (u16*)(W + 0);            // 4096x1024 bf16 (dead after csr_gemm0)
  u16*   zcatb = (u16*)(W + 0);            // 4096x320 bf16
  u16*   zzb   = (u16*)(W + 2621440);      // 4096x512 bf16
  u16*   h0b   = (u16*)(W + 8388608);      // 4096x512 bf16 (dead after agg0)
  u16*   h12b  = (u16*)(W + 8388608);      // 4096x512 bf16 (reuses h0b region)
  u16*   hb    = (u16*)(W + 12582912);     // 4096x576 bf16
  u16*   W0t   = (u16*)(W + 17301504);     // 512x1024
  u16*   W12t  = (u16*)(W + 18350080);     // 512x576
  u16*   fc1t  = (u16*)(W + 18939904);     // 512x320
  u16*   fc2t  = (u16*)(W + 19267584);     // 4096x512
  int*   nbr   = (int*)(W + 23461888);     // 4096x256 int
  int*   cnt   = (int*)(W + 27656192);     // 4096 int
  float* fs0   = (float*)(W + 27672576);   // fs0,fd0,fs1,fd1,fs2,fd2 contiguous
  float* fd0   = fs0 + 4096;
  float* fs1   = fd0 + 4096;
  float* fd1   = fs1 + 4096;
  float* fs2   = fd1 + 4096;
  float* fd2   = fs2 + 4096;

  // 1) small transposes + X convert + fs/fd zero
  prep_all<<<5080, 256, 0, stream>>>(W0, W0t, W1, W12t, W2, W12t + 256 * 576,
                                     fc1w, fc1t, X, Xb, fs0);

  // 2) gemm0 (+fused fsrc0) + CSR scan (wave-scan) + fc2 transpose, merged (R17-best)
  csr_gemm0<<<6400, 256, 0, stream>>>(Xb, W0t, h0b, (const unsigned*)adj, nbr, cnt,
                                      fc2w, fc2t, a0, fs0, fd0);

  // 3) layer-0 aggregate
  agg_gat0<<<1024, 256, 0, stream>>>(h0b, fs0, fd0, nbr, cnt, Y, hb);

  // 4) layers 1&2 GEMM (+fused fsrc12 atomics), K=576
  gemm_mfma64<0, true, 2><<<dim3(8, 32), 256, 0, stream>>>(
      hb, 576, W12t, 576, h12b, 512, 576, nullptr, a1, a2, fs1, fd1, fs2, fd2);

  // 5) layers 1&2 aggregate + reparam + concat
  agg_gat12<<<1024, 256, 0, stream>>>(h12b, fs1, fd1, fs2, fd2, nbr, cnt, noise, Y, zcatb);

  // 6) decoder fc1, K=320
  gemm_mfma64<1, true, 0><<<dim3(8, 32), 256, 0, stream>>>(
      zcatb, 320, fc1t, 320, zzb, 512, 320, fc1b,
      nullptr, nullptr, nullptr, nullptr, nullptr, nullptr);

  // 7) decoder fc2, K=512
  gemm_fc2_8p<<<dim3(16, 16), 512, 0, stream>>>(zzb, 512, fc2t, 512, out, 4096, 512, fc2b);
}